// Round 5
// baseline (70.462 us; speedup 1.0000x reference)
//
#include <hip/hip_runtime.h>
#include <cstdint>

// Ball query vs numpy-f32 reference. The reference's FP structure is
// heterogeneous and we replicate it exactly:
//   norms:   separate ufunc passes -> pure rn:  n = rn(rn(xx + yy) + zz)
//   dot:     BLAS sgemm K-loop     -> FMA chain: d = fma(z1,z2, fma(y1,y2, rn(x1*x2)))
//   combine: separate ufunc passes -> pure rn:  d2 = rn(rn(n1+n2) - rn(2*dot))
// hipcc defaults to -ffp-contract=fast which fuses ANY mul+add written as
// plain ops or __f*_rn intrinsics (they lower to plain IR) — rounds 1-4 all
// tested unintended variants because of this. contract(off) + explicit
// __fmaf_rn pins down each rounding exactly.
// Outputs (flat float32, concatenated):
//   [0          : N1*K)        mapping   (index as float; unfilled -> 0)
//   [N1*K       : N1*K+N1)     num_neighbors (min(count, K))
//   [N1*K+N1    : +N1*K*3)     gathered coords (unfilled -> 0)

#define BQ_K  32
#define BQ_N1 8192
#define BQ_N2 16384

__global__ __launch_bounds__(256) void ballquery_kernel(
    const float* __restrict__ p1,   // [N1,3]
    const float* __restrict__ p2,   // [N2,3]
    float* __restrict__ out) {
#pragma clang fp contract(off)
  const int lane = threadIdx.x & 63;
  const int wave = threadIdx.x >> 6;
  const int q = blockIdx.x * 4 + wave;
  if (q >= BQ_N1) return;

  // Query point (wave-uniform broadcast load).
  const float x1 = p1[q * 3 + 0];
  const float y1 = p1[q * 3 + 1];
  const float z1 = p1[q * 3 + 2];
  const float n1 = (x1 * x1 + y1 * y1) + z1 * z1;  // pure rn (contract off)
  // r^2: f64 0.08*0.08 cast to f32.
  const float rsq = (float)(0.08 * 0.08);

  float* __restrict__ mapO = out + (size_t)q * BQ_K;
  float* __restrict__ numO = out + (size_t)BQ_N1 * BQ_K + q;
  float* __restrict__ ptsO =
      out + (size_t)BQ_N1 * BQ_K + BQ_N1 + (size_t)q * BQ_K * 3;

  int filled = 0;  // wave-uniform; = min(count_so_far, K)
  for (int base = 0; base < BQ_N2; base += 64) {
    const int j = base + lane;
    const float x2 = p2[j * 3 + 0];
    const float y2 = p2[j * 3 + 1];
    const float z2 = p2[j * 3 + 2];
    // Pure-rn norm (separate ufunc passes in numpy; contract off keeps it).
    const float n2 = (x2 * x2 + y2 * y2) + z2 * z2;
    // BLAS sgemm K-loop: explicit FMA chain (pragma does not affect __fmaf_rn).
    float dot = x2 * x1;                 // rn(x1*x2) == fma(x1,x2,0)
    dot = __fmaf_rn(y1, y2, dot);
    dot = __fmaf_rn(z1, z2, dot);
    // Pure-rn combine.
    const float nsum = n1 + n2;
    const float twodot = 2.0f * dot;
    const float d2 = nsum - twodot;
    const bool within = (d2 <= rsq);
    const unsigned long long b = __ballot(within);
    if (b) {
      const int rank = __popcll(b & ((1ull << lane) - 1ull));
      const int slot = filled + rank;
      if (within && slot < BQ_K) {
        mapO[slot] = (float)j;
        ptsO[slot * 3 + 0] = x2;
        ptsO[slot * 3 + 1] = y2;
        ptsO[slot * 3 + 2] = z2;
      }
      filled += (int)__popcll(b);
      if (filled >= BQ_K) {
        filled = BQ_K;
        break;  // outputs saturated; num_neighbors = K
      }
    }
  }

  // Zero-fill unfilled slots (harness poisons d_out; we must write everything).
  for (int s = filled + lane; s < BQ_K; s += 64) {
    mapO[s] = 0.0f;
    ptsO[s * 3 + 0] = 0.0f;
    ptsO[s * 3 + 1] = 0.0f;
    ptsO[s * 3 + 2] = 0.0f;
  }
  if (lane == 0) numO[0] = (float)filled;
}

extern "C" void kernel_launch(void* const* d_in, const int* in_sizes, int n_in,
                              void* d_out, int out_size, void* d_ws,
                              size_t ws_size, hipStream_t stream) {
  const float* p1 = (const float*)d_in[0];
  const float* p2 = (const float*)d_in[1];
  float* out = (float*)d_out;
  // 4 waves per 256-thread block, one query per wave.
  const int blocks = BQ_N1 / 4;
  ballquery_kernel<<<blocks, 256, 0, stream>>>(p1, p2, out);
}

// Round 6
// 30.789 us; speedup vs baseline: 2.2885x; 2.2885x over previous
//
#include <hip/hip_runtime.h>
#include <cstdint>

// Ball query via spatial grid. Membership decision replicates the numpy-f32
// reference EXACTLY (verified round 5):
//   norms:   pure rn  n = rn(rn(xx + yy) + zz)         (ufunc passes)
//   dot:     FMA chain d = fma(z1,z2, fma(y1,y2, rn(x1*x2)))  (sgemm K-loop)
//   combine: pure rn  d2 = rn(rn(n1+n2) - rn(2*dot))
// hipcc's -ffp-contract=fast would fuse the plain-op chains -> every compute
// kernel body carries #pragma clang fp contract(off); the dot uses explicit
// __fmaf_rn (unaffected by the pragma). DO NOT ALTER THIS CHAIN.
//
// Grid: 12^3 cells, cell = 1/12 = 0.0833 > r = 0.08  =>  any point whose
// (FP-accepted) distance is <= r lies in the 27-neighborhood of the query's
// cell (per-axis |dx| <= sqrt(rsq + 3e-7) ~ 0.08000 < 0.0833). Counting-sort
// build per launch in d_ws; within-cell order is atomic-nondeterministic but
// the query ranks hits by index, so the OUTPUT is deterministic.
//
// Outputs (flat float32, concatenated):
//   [0          : N1*K)        mapping   (index as float; unfilled -> 0)
//   [N1*K       : N1*K+N1)     num_neighbors (min(count, K))
//   [N1*K+N1    : +N1*K*3)     gathered coords (unfilled -> 0)

#define BQ_K   32
#define BQ_N1  8192
#define BQ_N2  16384
#define GDIM   12
#define NCELLS (GDIM * GDIM * GDIM)  // 1728
#define HITCAP 128                   // max hits on fast path (data max ~60)

// d_ws layout (bytes):
#define WS_CNT_OFF    0        // int[NCELLS]
#define WS_START_OFF  8192     // int[NCELLS]
#define WS_CURSOR_OFF 16384    // int[NCELLS]
#define WS_SORTED_OFF 24576    // float4[BQ_N2]  (x,y,z, bitcast index)
#define WS_NEED       (WS_SORTED_OFF + BQ_N2 * 16)

__device__ __forceinline__ int bq_cell(float x, float y, float z) {
  int cx = min(max((int)(x * (float)GDIM), 0), GDIM - 1);
  int cy = min(max((int)(y * (float)GDIM), 0), GDIM - 1);
  int cz = min(max((int)(z * (float)GDIM), 0), GDIM - 1);
  return (cz * GDIM + cy) * GDIM + cx;
}

__global__ void bq_zero_kernel(int* __restrict__ cnt) {
  int i = blockIdx.x * blockDim.x + threadIdx.x;
  if (i < NCELLS) cnt[i] = 0;
}

__global__ void bq_count_kernel(const float* __restrict__ p2,
                                int* __restrict__ cnt) {
  int i = blockIdx.x * blockDim.x + threadIdx.x;
  if (i < BQ_N2)
    atomicAdd(&cnt[bq_cell(p2[i * 3], p2[i * 3 + 1], p2[i * 3 + 2])], 1);
}

// Exclusive scan of cnt[1728] -> start & cursor. One block, 256 threads,
// 7 cells/thread (1792 >= 1728), wave shfl-scan + cross-wave LDS.
__global__ __launch_bounds__(256) void bq_scan_kernel(
    const int* __restrict__ cnt, int* __restrict__ start,
    int* __restrict__ cursor) {
  __shared__ int s_wave[4];
  const int t = threadIdx.x;
  const int lane = t & 63, wid = t >> 6;
  const int base = t * 7;
  int loc[7];
  int sum = 0;
#pragma unroll
  for (int i = 0; i < 7; ++i) {
    int c = (base + i < NCELLS) ? cnt[base + i] : 0;
    loc[i] = sum;  // thread-local exclusive
    sum += c;
  }
  int inc = sum;  // wave-inclusive scan of thread sums
#pragma unroll
  for (int d = 1; d < 64; d <<= 1) {
    int v = __shfl_up(inc, d);
    if (lane >= d) inc += v;
  }
  if (lane == 63) s_wave[wid] = inc;
  __syncthreads();
  if (t == 0) {
    int r = 0;
    for (int w = 0; w < 4; ++w) { int v = s_wave[w]; s_wave[w] = r; r += v; }
  }
  __syncthreads();
  const int tb = s_wave[wid] + (inc - sum);
#pragma unroll
  for (int i = 0; i < 7; ++i) {
    int idx = base + i;
    if (idx < NCELLS) {
      start[idx] = tb + loc[i];
      cursor[idx] = tb + loc[i];
    }
  }
}

__global__ void bq_scatter_kernel(const float* __restrict__ p2,
                                  int* __restrict__ cursor,
                                  float4* __restrict__ sorted) {
  int i = blockIdx.x * blockDim.x + threadIdx.x;
  if (i < BQ_N2) {
    const float x = p2[i * 3], y = p2[i * 3 + 1], z = p2[i * 3 + 2];
    const int slot = atomicAdd(&cursor[bq_cell(x, y, z)], 1);
    sorted[slot] = make_float4(x, y, z, __int_as_float(i));
  }
}

__global__ __launch_bounds__(256) void bq_query_kernel(
    const float* __restrict__ p1, const float* __restrict__ p2,
    const int* __restrict__ cnt, const int* __restrict__ start,
    const float4* __restrict__ sorted, float* __restrict__ out) {
#pragma clang fp contract(off)
  const int lane = threadIdx.x & 63;
  const int wid = threadIdx.x >> 6;
  const int q = blockIdx.x * 4 + wid;

  __shared__ int s_pref[4][28];
  __shared__ int s_st[4][27];
  __shared__ int s_hits[4][HITCAP];

  const float x1 = p1[q * 3 + 0];
  const float y1 = p1[q * 3 + 1];
  const float z1 = p1[q * 3 + 2];
  const float n1 = (x1 * x1 + y1 * y1) + z1 * z1;  // pure rn (contract off)
  const float rsq = (float)(0.08 * 0.08);

  const int cx = min(max((int)(x1 * (float)GDIM), 0), GDIM - 1);
  const int cy = min(max((int)(y1 * (float)GDIM), 0), GDIM - 1);
  const int cz = min(max((int)(z1 * (float)GDIM), 0), GDIM - 1);

  // Lanes 0..26: one neighbor cell each.
  int mycnt = 0, myst = 0;
  if (lane < 27) {
    const int nx = cx + (lane % 3) - 1;
    const int ny = cy + ((lane / 3) % 3) - 1;
    const int nz = cz + (lane / 9) - 1;
    if (nx >= 0 && nx < GDIM && ny >= 0 && ny < GDIM && nz >= 0 && nz < GDIM) {
      const int cc = (nz * GDIM + ny) * GDIM + nx;
      mycnt = cnt[cc];
      myst = start[cc];
    }
  }
  // Wave-inclusive scan of counts (lanes >= 27 contribute 0).
  int incs = mycnt;
#pragma unroll
  for (int d = 1; d < 64; d <<= 1) {
    int v = __shfl_up(incs, d);
    if (lane >= d) incs += v;
  }
  const int T = __shfl(incs, 63);
  const int myexcl = incs - mycnt;
  if (lane < 27) {
    s_st[wid][lane] = myst;
    s_pref[wid][lane] = myexcl;
  }
  if (lane == 27) s_pref[wid][27] = myexcl;  // == T

  // Flattened candidate sweep; collect hit indices into per-wave LDS.
  int H = 0;
  for (int s0 = 0; s0 < T; s0 += 64) {
    const int s = s0 + lane;
    bool within = false;
    int idx = 0;
    if (s < T) {
      // lower_bound over s_pref[0..27]: largest c with pref[c] <= s.
      int lo = 0, hi = 27;
#pragma unroll
      for (int it = 0; it < 5; ++it) {
        const int mid = (lo + hi) >> 1;
        const bool ge = (s_pref[wid][mid] <= s);
        lo = ge ? mid : lo;
        hi = ge ? hi : mid;
      }
      const int g = s_st[wid][lo] + (s - s_pref[wid][lo]);
      const float4 pt = sorted[g];
      const float x2 = pt.x, y2 = pt.y, z2 = pt.z;
      idx = __float_as_int(pt.w);
      // EXACT reference FP chain (round 5) — do not alter.
      const float n2 = (x2 * x2 + y2 * y2) + z2 * z2;
      float dot = x2 * x1;
      dot = __fmaf_rn(y1, y2, dot);
      dot = __fmaf_rn(z1, z2, dot);
      const float nsum = n1 + n2;
      const float twodot = 2.0f * dot;
      const float d2 = nsum - twodot;
      within = (d2 <= rsq);
    }
    const unsigned long long b = __ballot(within);
    if (b) {
      if (within) {
        const int pos = H + (int)__popcll(b & ((1ull << lane) - 1ull));
        if (pos < HITCAP) s_hits[wid][pos] = idx;
      }
      H += (int)__popcll(b);
    }
  }

  float* __restrict__ mapO = out + (size_t)q * BQ_K;
  float* __restrict__ numO = out + (size_t)BQ_N1 * BQ_K + q;
  float* __restrict__ ptsO =
      out + (size_t)BQ_N1 * BQ_K + BQ_N1 + (size_t)q * BQ_K * 3;

  if (H <= HITCAP) {
    const int nh = min(H, BQ_K);
    const int me0 = (lane < H) ? s_hits[wid][lane] : 0x7fffffff;
    const int me1 = (lane + 64 < H) ? s_hits[wid][lane + 64] : 0x7fffffff;
    int r0 = 0, r1 = 0;
    for (int j = 0; j < H; ++j) {  // broadcast LDS reads, conflict-free
      const int bj = s_hits[wid][j];
      r0 += (bj < me0) ? 1 : 0;
      r1 += (bj < me1) ? 1 : 0;
    }
    if (lane < H && r0 < BQ_K) {
      mapO[r0] = (float)me0;
      ptsO[r0 * 3 + 0] = p2[me0 * 3 + 0];
      ptsO[r0 * 3 + 1] = p2[me0 * 3 + 1];
      ptsO[r0 * 3 + 2] = p2[me0 * 3 + 2];
    }
    if (lane + 64 < H && r1 < BQ_K) {
      mapO[r1] = (float)me1;
      ptsO[r1 * 3 + 0] = p2[me1 * 3 + 0];
      ptsO[r1 * 3 + 1] = p2[me1 * 3 + 1];
      ptsO[r1 * 3 + 2] = p2[me1 * 3 + 2];
    }
    for (int sF = nh + lane; sF < BQ_K; sF += 64) {
      mapO[sF] = 0.0f;
      ptsO[sF * 3 + 0] = 0.0f;
      ptsO[sF * 3 + 1] = 0.0f;
      ptsO[sF * 3 + 2] = 0.0f;
    }
    if (lane == 0) numO[0] = (float)nh;
  } else {
    // Exact sequential fallback (never expected; correctness safety net).
    int filled = 0;
    for (int base = 0; base < BQ_N2; base += 64) {
      const int j = base + lane;
      const float x2 = p2[j * 3 + 0];
      const float y2 = p2[j * 3 + 1];
      const float z2 = p2[j * 3 + 2];
      const float n2 = (x2 * x2 + y2 * y2) + z2 * z2;
      float dot = x2 * x1;
      dot = __fmaf_rn(y1, y2, dot);
      dot = __fmaf_rn(z1, z2, dot);
      const float d2 = (n1 + n2) - 2.0f * dot;
      const bool within = (d2 <= rsq);
      const unsigned long long b = __ballot(within);
      if (b) {
        const int rank = (int)__popcll(b & ((1ull << lane) - 1ull));
        const int slot = filled + rank;
        if (within && slot < BQ_K) {
          mapO[slot] = (float)j;
          ptsO[slot * 3 + 0] = x2;
          ptsO[slot * 3 + 1] = y2;
          ptsO[slot * 3 + 2] = z2;
        }
        filled += (int)__popcll(b);
        if (filled >= BQ_K) { filled = BQ_K; break; }
      }
    }
    for (int sF = filled + lane; sF < BQ_K; sF += 64) {
      mapO[sF] = 0.0f;
      ptsO[sF * 3 + 0] = 0.0f;
      ptsO[sF * 3 + 1] = 0.0f;
      ptsO[sF * 3 + 2] = 0.0f;
    }
    if (lane == 0) numO[0] = (float)filled;
  }
}

// Round-5 brute-force kernel, kept as whole-problem fallback if ws too small.
__global__ __launch_bounds__(256) void bq_seq_kernel(
    const float* __restrict__ p1, const float* __restrict__ p2,
    float* __restrict__ out) {
#pragma clang fp contract(off)
  const int lane = threadIdx.x & 63;
  const int wave = threadIdx.x >> 6;
  const int q = blockIdx.x * 4 + wave;
  const float x1 = p1[q * 3 + 0], y1 = p1[q * 3 + 1], z1 = p1[q * 3 + 2];
  const float n1 = (x1 * x1 + y1 * y1) + z1 * z1;
  const float rsq = (float)(0.08 * 0.08);
  float* mapO = out + (size_t)q * BQ_K;
  float* numO = out + (size_t)BQ_N1 * BQ_K + q;
  float* ptsO = out + (size_t)BQ_N1 * BQ_K + BQ_N1 + (size_t)q * BQ_K * 3;
  int filled = 0;
  for (int base = 0; base < BQ_N2; base += 64) {
    const int j = base + lane;
    const float x2 = p2[j * 3 + 0], y2 = p2[j * 3 + 1], z2 = p2[j * 3 + 2];
    const float n2 = (x2 * x2 + y2 * y2) + z2 * z2;
    float dot = x2 * x1;
    dot = __fmaf_rn(y1, y2, dot);
    dot = __fmaf_rn(z1, z2, dot);
    const float d2 = (n1 + n2) - 2.0f * dot;
    const bool within = (d2 <= rsq);
    const unsigned long long b = __ballot(within);
    if (b) {
      const int rank = (int)__popcll(b & ((1ull << lane) - 1ull));
      const int slot = filled + rank;
      if (within && slot < BQ_K) {
        mapO[slot] = (float)j;
        ptsO[slot * 3 + 0] = x2;
        ptsO[slot * 3 + 1] = y2;
        ptsO[slot * 3 + 2] = z2;
      }
      filled += (int)__popcll(b);
      if (filled >= BQ_K) { filled = BQ_K; break; }
    }
  }
  for (int s = filled + lane; s < BQ_K; s += 64) {
    mapO[s] = 0.0f;
    ptsO[s * 3 + 0] = 0.0f;
    ptsO[s * 3 + 1] = 0.0f;
    ptsO[s * 3 + 2] = 0.0f;
  }
  if (lane == 0) numO[0] = (float)filled;
}

extern "C" void kernel_launch(void* const* d_in, const int* in_sizes, int n_in,
                              void* d_out, int out_size, void* d_ws,
                              size_t ws_size, hipStream_t stream) {
  const float* p1 = (const float*)d_in[0];
  const float* p2 = (const float*)d_in[1];
  float* out = (float*)d_out;

  if (ws_size < (size_t)WS_NEED) {
    bq_seq_kernel<<<BQ_N1 / 4, 256, 0, stream>>>(p1, p2, out);
    return;
  }

  char* ws = (char*)d_ws;
  int* cnt = (int*)(ws + WS_CNT_OFF);
  int* start = (int*)(ws + WS_START_OFF);
  int* cursor = (int*)(ws + WS_CURSOR_OFF);
  float4* sorted = (float4*)(ws + WS_SORTED_OFF);

  bq_zero_kernel<<<(NCELLS + 255) / 256, 256, 0, stream>>>(cnt);
  bq_count_kernel<<<BQ_N2 / 256, 256, 0, stream>>>(p2, cnt);
  bq_scan_kernel<<<1, 256, 0, stream>>>(cnt, start, cursor);
  bq_scatter_kernel<<<BQ_N2 / 256, 256, 0, stream>>>(p2, cursor, sorted);
  bq_query_kernel<<<BQ_N1 / 4, 256, 0, stream>>>(p1, p2, cnt, start, sorted,
                                                 out);
}

// Round 7
// 28.253 us; speedup vs baseline: 2.4940x; 1.0898x over previous
//
#include <hip/hip_runtime.h>
#include <cstdint>

// Ball query via spatial grid, 2 dispatches (fused build + query).
// Membership decision replicates the numpy-f32 reference EXACTLY (round 5):
//   norms:   pure rn  n = rn(rn(xx + yy) + zz)         (ufunc passes)
//   dot:     FMA chain d = fma(z1,z2, fma(y1,y2, rn(x1*x2)))  (sgemm K-loop)
//   combine: pure rn  d2 = rn(rn(n1+n2) - rn(2*dot))
// hipcc's -ffp-contract=fast would fuse the plain-op chains -> compute kernels
// carry #pragma clang fp contract(off); the dot uses explicit __fmaf_rn.
// DO NOT ALTER THIS CHAIN.
//
// Grid: 12^3 cells, cell = 1/12 = 0.0833 > max accepted distance ~0.08000
// => any FP-accepted neighbor is within the 27-cell neighborhood (margin
// 0.0033 >> 1e-7 FP slop). Within-cell order is atomic-nondeterministic but
// the query ranks hits by index, so the OUTPUT is deterministic.
//
// Outputs (flat float32, concatenated):
//   [0          : N1*K)        mapping   (index as float; unfilled -> 0)
//   [N1*K       : N1*K+N1)     num_neighbors (min(count, K))
//   [N1*K+N1    : +N1*K*3)     gathered coords (unfilled -> 0)

#define BQ_K   32
#define BQ_N1  8192
#define BQ_N2  16384
#define GDIM   12
#define NCELLS (GDIM * GDIM * GDIM)  // 1728
#define HITCAP 128                   // max hits on fast path (data max ~60)

// d_ws layout (bytes):
#define WS_CNT_OFF    0                   // int[NCELLS]
#define WS_START_OFF  (NCELLS * 4)        // int[NCELLS]   (6912)
#define WS_SORTED_OFF (2 * NCELLS * 4)    // float4[BQ_N2] (13824, 16B-aligned)
#define WS_NEED       (WS_SORTED_OFF + BQ_N2 * 16)

__device__ __forceinline__ int bq_cell(float x, float y, float z) {
  int cx = min(max((int)(x * (float)GDIM), 0), GDIM - 1);
  int cy = min(max((int)(y * (float)GDIM), 0), GDIM - 1);
  int cz = min(max((int)(z * (float)GDIM), 0), GDIM - 1);
  return (cz * GDIM + cy) * GDIM + cx;
}

// Fused grid build: zero + count + scan + scatter in ONE workgroup.
// 1024 threads x 16 points each; points cached in VGPRs (static unroll).
__global__ __launch_bounds__(1024) void bq_build_kernel(
    const float* __restrict__ p2, int* __restrict__ cnt_g,
    int* __restrict__ start_g, float4* __restrict__ sorted) {
  __shared__ int s_cnt[NCELLS];  // counts, then cursors (exclusive starts)
  __shared__ int s_wave[16];
  const int t = threadIdx.x;
  const int lane = t & 63, wv = t >> 6;

  for (int i = t; i < NCELLS; i += 1024) s_cnt[i] = 0;
  __syncthreads();

  float px[16], py[16], pz[16];
  int pc[16];
#pragma unroll
  for (int k = 0; k < 16; ++k) {
    const int i = k * 1024 + t;  // coalesced across the block
    px[k] = p2[i * 3 + 0];
    py[k] = p2[i * 3 + 1];
    pz[k] = p2[i * 3 + 2];
    pc[k] = bq_cell(px[k], py[k], pz[k]);
    atomicAdd(&s_cnt[pc[k]], 1);
  }
  __syncthreads();

  // Exclusive scan of s_cnt[1728]: 2 cells/thread (threads 0..863 active).
  const int cell0 = t * 2;
  int c0 = 0, c1 = 0;
  if (cell0 < NCELLS) {
    c0 = s_cnt[cell0];
    c1 = s_cnt[cell0 + 1];
  }
  const int sum = c0 + c1;
  int inc = sum;
#pragma unroll
  for (int d = 1; d < 64; d <<= 1) {
    int v = __shfl_up(inc, d);
    if (lane >= d) inc += v;
  }
  if (lane == 63) s_wave[wv] = inc;
  __syncthreads();  // also: all counts read before overwrite below
  if (t == 0) {
    int r = 0;
    for (int w = 0; w < 16; ++w) { int v = s_wave[w]; s_wave[w] = r; r += v; }
  }
  __syncthreads();
  const int excl = s_wave[wv] + (inc - sum);
  if (cell0 < NCELLS) {
    cnt_g[cell0] = c0;
    cnt_g[cell0 + 1] = c1;
    start_g[cell0] = excl;
    start_g[cell0 + 1] = excl + c0;
    s_cnt[cell0] = excl;          // becomes cursor
    s_cnt[cell0 + 1] = excl + c0;
  }
  __syncthreads();

  // Scatter from registers via LDS cursors.
#pragma unroll
  for (int k = 0; k < 16; ++k) {
    const int i = k * 1024 + t;
    const int slot = atomicAdd(&s_cnt[pc[k]], 1);
    sorted[slot] = make_float4(px[k], py[k], pz[k], __int_as_float(i));
  }
}

__global__ __launch_bounds__(256) void bq_query_kernel(
    const float* __restrict__ p1, const float* __restrict__ p2,
    const int* __restrict__ cnt, const int* __restrict__ start,
    const float4* __restrict__ sorted, float* __restrict__ out) {
#pragma clang fp contract(off)
  const int lane = threadIdx.x & 63;
  const int wid = threadIdx.x >> 6;
  const int q = blockIdx.x * 4 + wid;

  __shared__ int s_pref[4][28];
  __shared__ int s_st[4][27];
  __shared__ float4 s_hits[4][HITCAP];  // (x, y, z, bitcast idx)

  const float x1 = p1[q * 3 + 0];
  const float y1 = p1[q * 3 + 1];
  const float z1 = p1[q * 3 + 2];
  const float n1 = (x1 * x1 + y1 * y1) + z1 * z1;  // pure rn (contract off)
  const float rsq = (float)(0.08 * 0.08);

  const int cx = min(max((int)(x1 * (float)GDIM), 0), GDIM - 1);
  const int cy = min(max((int)(y1 * (float)GDIM), 0), GDIM - 1);
  const int cz = min(max((int)(z1 * (float)GDIM), 0), GDIM - 1);

  // Lanes 0..26: one neighbor cell each.
  int mycnt = 0, myst = 0;
  if (lane < 27) {
    const int nx = cx + (lane % 3) - 1;
    const int ny = cy + ((lane / 3) % 3) - 1;
    const int nz = cz + (lane / 9) - 1;
    if (nx >= 0 && nx < GDIM && ny >= 0 && ny < GDIM && nz >= 0 && nz < GDIM) {
      const int cc = (nz * GDIM + ny) * GDIM + nx;
      mycnt = cnt[cc];
      myst = start[cc];
    }
  }
  // Wave-inclusive scan of counts (lanes >= 27 contribute 0).
  int incs = mycnt;
#pragma unroll
  for (int d = 1; d < 64; d <<= 1) {
    int v = __shfl_up(incs, d);
    if (lane >= d) incs += v;
  }
  const int T = __shfl(incs, 63);
  const int myexcl = incs - mycnt;
  if (lane < 27) {
    s_st[wid][lane] = myst;
    s_pref[wid][lane] = myexcl;
  }
  if (lane == 27) s_pref[wid][27] = myexcl;  // == T

  // Flattened candidate sweep; collect hits (coords+idx) into per-wave LDS.
  int H = 0;
  for (int s0 = 0; s0 < T; s0 += 64) {
    const int s = s0 + lane;
    bool within = false;
    float x2 = 0.f, y2 = 0.f, z2 = 0.f;
    int idx = 0;
    if (s < T) {
      // lower_bound over s_pref[0..27]: largest c with pref[c] <= s.
      int lo = 0, hi = 27;
#pragma unroll
      for (int it = 0; it < 5; ++it) {
        const int mid = (lo + hi) >> 1;
        const bool ge = (s_pref[wid][mid] <= s);
        lo = ge ? mid : lo;
        hi = ge ? hi : mid;
      }
      const int g = s_st[wid][lo] + (s - s_pref[wid][lo]);
      const float4 pt = sorted[g];
      x2 = pt.x; y2 = pt.y; z2 = pt.z;
      idx = __float_as_int(pt.w);
      // EXACT reference FP chain (round 5) — do not alter.
      const float n2 = (x2 * x2 + y2 * y2) + z2 * z2;
      float dot = x2 * x1;
      dot = __fmaf_rn(y1, y2, dot);
      dot = __fmaf_rn(z1, z2, dot);
      const float nsum = n1 + n2;
      const float twodot = 2.0f * dot;
      const float d2 = nsum - twodot;
      within = (d2 <= rsq);
    }
    const unsigned long long b = __ballot(within);
    if (b) {
      if (within) {
        const int pos = H + (int)__popcll(b & ((1ull << lane) - 1ull));
        if (pos < HITCAP)
          s_hits[wid][pos] = make_float4(x2, y2, z2, __int_as_float(idx));
      }
      H += (int)__popcll(b);
    }
  }

  float* __restrict__ mapO = out + (size_t)q * BQ_K;
  float* __restrict__ numO = out + (size_t)BQ_N1 * BQ_K + q;
  float* __restrict__ ptsO =
      out + (size_t)BQ_N1 * BQ_K + BQ_N1 + (size_t)q * BQ_K * 3;

  if (H <= HITCAP) {
    const int nh = min(H, BQ_K);
    float4 h0 = make_float4(0.f, 0.f, 0.f, __int_as_float(0x7fffffff));
    float4 h1 = h0;
    if (lane < H) h0 = s_hits[wid][lane];
    if (lane + 64 < H) h1 = s_hits[wid][lane + 64];
    const int i0 = __float_as_int(h0.w);
    const int i1 = __float_as_int(h1.w);
    int r0 = 0, r1 = 0;
    for (int j = 0; j < H; ++j) {  // broadcast LDS reads, conflict-free
      const int bj = __float_as_int(s_hits[wid][j].w);
      r0 += (bj < i0) ? 1 : 0;
      r1 += (bj < i1) ? 1 : 0;
    }
    if (lane < H && r0 < BQ_K) {
      mapO[r0] = (float)i0;
      ptsO[r0 * 3 + 0] = h0.x;
      ptsO[r0 * 3 + 1] = h0.y;
      ptsO[r0 * 3 + 2] = h0.z;
    }
    if (lane + 64 < H && r1 < BQ_K) {
      mapO[r1] = (float)i1;
      ptsO[r1 * 3 + 0] = h1.x;
      ptsO[r1 * 3 + 1] = h1.y;
      ptsO[r1 * 3 + 2] = h1.z;
    }
    for (int sF = nh + lane; sF < BQ_K; sF += 64) {
      mapO[sF] = 0.0f;
      ptsO[sF * 3 + 0] = 0.0f;
      ptsO[sF * 3 + 1] = 0.0f;
      ptsO[sF * 3 + 2] = 0.0f;
    }
    if (lane == 0) numO[0] = (float)nh;
  } else {
    // Exact sequential fallback (never expected; correctness safety net).
    int filled = 0;
    for (int base = 0; base < BQ_N2; base += 64) {
      const int j = base + lane;
      const float x2 = p2[j * 3 + 0];
      const float y2 = p2[j * 3 + 1];
      const float z2 = p2[j * 3 + 2];
      const float n2 = (x2 * x2 + y2 * y2) + z2 * z2;
      float dot = x2 * x1;
      dot = __fmaf_rn(y1, y2, dot);
      dot = __fmaf_rn(z1, z2, dot);
      const float d2 = (n1 + n2) - 2.0f * dot;
      const bool within = (d2 <= rsq);
      const unsigned long long b = __ballot(within);
      if (b) {
        const int rank = (int)__popcll(b & ((1ull << lane) - 1ull));
        const int slot = filled + rank;
        if (within && slot < BQ_K) {
          mapO[slot] = (float)j;
          ptsO[slot * 3 + 0] = x2;
          ptsO[slot * 3 + 1] = y2;
          ptsO[slot * 3 + 2] = z2;
        }
        filled += (int)__popcll(b);
        if (filled >= BQ_K) { filled = BQ_K; break; }
      }
    }
    for (int sF = filled + lane; sF < BQ_K; sF += 64) {
      mapO[sF] = 0.0f;
      ptsO[sF * 3 + 0] = 0.0f;
      ptsO[sF * 3 + 1] = 0.0f;
      ptsO[sF * 3 + 2] = 0.0f;
    }
    if (lane == 0) numO[0] = (float)filled;
  }
}

// Round-5 brute-force kernel, kept as whole-problem fallback if ws too small.
__global__ __launch_bounds__(256) void bq_seq_kernel(
    const float* __restrict__ p1, const float* __restrict__ p2,
    float* __restrict__ out) {
#pragma clang fp contract(off)
  const int lane = threadIdx.x & 63;
  const int wave = threadIdx.x >> 6;
  const int q = blockIdx.x * 4 + wave;
  const float x1 = p1[q * 3 + 0], y1 = p1[q * 3 + 1], z1 = p1[q * 3 + 2];
  const float n1 = (x1 * x1 + y1 * y1) + z1 * z1;
  const float rsq = (float)(0.08 * 0.08);
  float* mapO = out + (size_t)q * BQ_K;
  float* numO = out + (size_t)BQ_N1 * BQ_K + q;
  float* ptsO = out + (size_t)BQ_N1 * BQ_K + BQ_N1 + (size_t)q * BQ_K * 3;
  int filled = 0;
  for (int base = 0; base < BQ_N2; base += 64) {
    const int j = base + lane;
    const float x2 = p2[j * 3 + 0], y2 = p2[j * 3 + 1], z2 = p2[j * 3 + 2];
    const float n2 = (x2 * x2 + y2 * y2) + z2 * z2;
    float dot = x2 * x1;
    dot = __fmaf_rn(y1, y2, dot);
    dot = __fmaf_rn(z1, z2, dot);
    const float d2 = (n1 + n2) - 2.0f * dot;
    const bool within = (d2 <= rsq);
    const unsigned long long b = __ballot(within);
    if (b) {
      const int rank = (int)__popcll(b & ((1ull << lane) - 1ull));
      const int slot = filled + rank;
      if (within && slot < BQ_K) {
        mapO[slot] = (float)j;
        ptsO[slot * 3 + 0] = x2;
        ptsO[slot * 3 + 1] = y2;
        ptsO[slot * 3 + 2] = z2;
      }
      filled += (int)__popcll(b);
      if (filled >= BQ_K) { filled = BQ_K; break; }
    }
  }
  for (int s = filled + lane; s < BQ_K; s += 64) {
    mapO[s] = 0.0f;
    ptsO[s * 3 + 0] = 0.0f;
    ptsO[s * 3 + 1] = 0.0f;
    ptsO[s * 3 + 2] = 0.0f;
  }
  if (lane == 0) numO[0] = (float)filled;
}

extern "C" void kernel_launch(void* const* d_in, const int* in_sizes, int n_in,
                              void* d_out, int out_size, void* d_ws,
                              size_t ws_size, hipStream_t stream) {
  const float* p1 = (const float*)d_in[0];
  const float* p2 = (const float*)d_in[1];
  float* out = (float*)d_out;

  if (ws_size < (size_t)WS_NEED) {
    bq_seq_kernel<<<BQ_N1 / 4, 256, 0, stream>>>(p1, p2, out);
    return;
  }

  char* ws = (char*)d_ws;
  int* cnt = (int*)(ws + WS_CNT_OFF);
  int* start = (int*)(ws + WS_START_OFF);
  float4* sorted = (float4*)(ws + WS_SORTED_OFF);

  bq_build_kernel<<<1, 1024, 0, stream>>>(p2, cnt, start, sorted);
  bq_query_kernel<<<BQ_N1 / 4, 256, 0, stream>>>(p1, p2, cnt, start, sorted,
                                                 out);
}

// Round 8
// 20.790 us; speedup vs baseline: 3.3892x; 1.3590x over previous
//
#include <hip/hip_runtime.h>
#include <cstdint>

// Ball query via 4-way-partitioned spatial grid, 2 dispatches.
// Membership decision replicates the numpy-f32 reference EXACTLY (round 5):
//   norms:   pure rn  n = rn(rn(xx + yy) + zz)         (ufunc passes)
//   dot:     FMA chain d = fma(z1,z2, fma(y1,y2, rn(x1*x2)))  (sgemm K-loop)
//   combine: pure rn  d2 = rn(rn(n1+n2) - rn(2*dot))
// hipcc's -ffp-contract=fast would fuse the plain-op chains -> compute kernels
// carry #pragma clang fp contract(off); the dot uses explicit __fmaf_rn.
// DO NOT ALTER THIS CHAIN.
//
// Grid: 12^3 cells, cell 1/12 = 0.0833 > max accepted distance ~0.08000 =>
// any FP-accepted neighbor lies in the 27-cell neighborhood. Points are
// striped into P=4 partitions; partition p's sub-grid occupies
// sorted[p*4096 .. +4096) with its own cnt/start arrays -> build is 4
// independent workgroups, no cross-WG sync. Query merges 108 (cell,part)
// runs; output is ranked by index so atomic scatter order doesn't matter.
// Cells whose AABB min-dist^2 to the query exceeds rsq*1.002 are pruned
// (margin 1.2e-5 >> total FP slop ~1e-6 -> no accepted point lost).
//
// Outputs (flat float32, concatenated):
//   [0          : N1*K)        mapping   (index as float; unfilled -> 0)
//   [N1*K       : N1*K+N1)     num_neighbors (min(count, K))
//   [N1*K+N1    : +N1*K*3)     gathered coords (unfilled -> 0)

#define BQ_K    32
#define BQ_N1   8192
#define BQ_N2   16384
#define GDIM    12
#define NCELLS  (GDIM * GDIM * GDIM)  // 1728
#define NPART   4
#define PPTS    (BQ_N2 / NPART)       // 4096 exactly per partition
#define NPAIRS  (27 * NPART)          // 108
#define HITCAP  128                   // max hits on fast path (data max ~60)
#define GIDXCAP 512                   // max candidates on fast path (avg ~180)

// d_ws layout (bytes):
#define WS_CNT_OFF    0                          // int[NPART][NCELLS]
#define WS_START_OFF  (NPART * NCELLS * 4)       // int[NPART][NCELLS] (27648)
#define WS_SORTED_OFF (2 * NPART * NCELLS * 4)   // float4[BQ_N2] (55296, 16B ok)
#define WS_NEED       (WS_SORTED_OFF + BQ_N2 * 16)

__device__ __forceinline__ int bq_cell(float x, float y, float z) {
  int cx = min(max((int)(x * (float)GDIM), 0), GDIM - 1);
  int cy = min(max((int)(y * (float)GDIM), 0), GDIM - 1);
  int cz = min(max((int)(z * (float)GDIM), 0), GDIM - 1);
  return (cz * GDIM + cy) * GDIM + cx;
}

// Grid build: 4 workgroups, each builds its partition's sub-grid.
__global__ __launch_bounds__(1024) void bq_build_kernel(
    const float* __restrict__ p2, int* __restrict__ cnt_g,
    int* __restrict__ start_g, float4* __restrict__ sorted) {
  __shared__ int s_cnt[NCELLS];  // counts, then absolute cursors
  __shared__ int s_wave[16];
  const int t = threadIdx.x;
  const int lane = t & 63, wv = t >> 6;
  const int p = blockIdx.x;
  const int pbase = p * PPTS;

  for (int i = t; i < NCELLS; i += 1024) s_cnt[i] = 0;
  __syncthreads();

  float px[4], py[4], pz[4];
  int pc[4];
#pragma unroll
  for (int k = 0; k < 4; ++k) {
    const int i = pbase + k * 1024 + t;  // coalesced
    px[k] = p2[i * 3 + 0];
    py[k] = p2[i * 3 + 1];
    pz[k] = p2[i * 3 + 2];
    pc[k] = bq_cell(px[k], py[k], pz[k]);
    atomicAdd(&s_cnt[pc[k]], 1);
  }
  __syncthreads();

  // Exclusive scan of s_cnt[1728]: 2 cells/thread (threads 0..863 active).
  const int cell0 = t * 2;
  int c0 = 0, c1 = 0;
  if (cell0 < NCELLS) {
    c0 = s_cnt[cell0];
    c1 = s_cnt[cell0 + 1];
  }
  const int sum = c0 + c1;
  int inc = sum;
#pragma unroll
  for (int d = 1; d < 64; d <<= 1) {
    int v = __shfl_up(inc, d);
    if (lane >= d) inc += v;
  }
  if (lane == 63) s_wave[wv] = inc;
  __syncthreads();  // all counts read before cursor overwrite below
  if (t == 0) {
    int r = 0;
    for (int w = 0; w < 16; ++w) { int v = s_wave[w]; s_wave[w] = r; r += v; }
  }
  __syncthreads();
  const int excl = s_wave[wv] + (inc - sum);
  if (cell0 < NCELLS) {
    cnt_g[p * NCELLS + cell0] = c0;
    cnt_g[p * NCELLS + cell0 + 1] = c1;
    start_g[p * NCELLS + cell0] = pbase + excl;
    start_g[p * NCELLS + cell0 + 1] = pbase + excl + c0;
    s_cnt[cell0] = pbase + excl;          // absolute cursor
    s_cnt[cell0 + 1] = pbase + excl + c0;
  }
  __syncthreads();

  // Scatter from registers via LDS cursors (absolute slots).
#pragma unroll
  for (int k = 0; k < 4; ++k) {
    const int i = pbase + k * 1024 + t;
    const int slot = atomicAdd(&s_cnt[pc[k]], 1);
    sorted[slot] = make_float4(px[k], py[k], pz[k], __int_as_float(i));
  }
}

__global__ __launch_bounds__(256) void bq_query_kernel(
    const float* __restrict__ p1, const float* __restrict__ p2,
    const int* __restrict__ cnt, const int* __restrict__ start,
    const float4* __restrict__ sorted, float* __restrict__ out) {
#pragma clang fp contract(off)
  const int lane = threadIdx.x & 63;
  const int wid = threadIdx.x >> 6;
  const int q = blockIdx.x * 4 + wid;

  __shared__ int s_gidx[4][GIDXCAP];    // candidate -> global sorted index
  __shared__ float4 s_hits[4][HITCAP];  // (x, y, z, bitcast idx)

  const float x1 = p1[q * 3 + 0];
  const float y1 = p1[q * 3 + 1];
  const float z1 = p1[q * 3 + 2];
  const float n1 = (x1 * x1 + y1 * y1) + z1 * z1;  // pure rn (contract off)
  const float rsq = (float)(0.08 * 0.08);
  const float prune_thr = 0.006413f;  // rsq*1.002: safe AABB prune bound

  const int cx = min(max((int)(x1 * (float)GDIM), 0), GDIM - 1);
  const int cy = min(max((int)(y1 * (float)GDIM), 0), GDIM - 1);
  const int cz = min(max((int)(z1 * (float)GDIM), 0), GDIM - 1);

  // Each lane owns 2 (cell,part) pairs: pr = 2*lane, 2*lane+1 (108 pairs).
  int c0 = 0, st0 = 0, c1 = 0, st1 = 0;
  if (lane < NPAIRS / 2) {
#pragma unroll
    for (int m = 0; m < 2; ++m) {
      const int pr = 2 * lane + m;
      const int ci = pr >> 2;       // 0..26 neighbor cell
      const int part = pr & 3;      // partition
      const int nx = cx + (ci % 3) - 1;
      const int ny = cy + ((ci / 3) % 3) - 1;
      const int nz = cz + (ci / 9) - 1;
      if (nx >= 0 && nx < GDIM && ny >= 0 && ny < GDIM && nz >= 0 &&
          nz < GDIM) {
        // AABB min-dist^2 prune (conservative; margin >> FP slop).
        const float lx = (float)nx / 12.0f, hx = (float)(nx + 1) / 12.0f;
        const float ly = (float)ny / 12.0f, hy = (float)(ny + 1) / 12.0f;
        const float lz = (float)nz / 12.0f, hz = (float)(nz + 1) / 12.0f;
        const float dx = fmaxf(0.0f, fmaxf(lx - x1, x1 - hx));
        const float dy = fmaxf(0.0f, fmaxf(ly - y1, y1 - hy));
        const float dz = fmaxf(0.0f, fmaxf(lz - z1, z1 - hz));
        const float mind2 = dx * dx + dy * dy + dz * dz;
        if (mind2 <= prune_thr) {
          const int cc = (nz * GDIM + ny) * GDIM + nx;
          const int v = cnt[part * NCELLS + cc];
          const int s = start[part * NCELLS + cc];
          if (m == 0) { c0 = v; st0 = s; } else { c1 = v; st1 = s; }
        }
      }
    }
  }
  // Wave-inclusive scan of per-lane sums -> per-pair exclusive prefixes.
  const int lsum = c0 + c1;
  int inc = lsum;
#pragma unroll
  for (int d = 1; d < 64; d <<= 1) {
    int v = __shfl_up(inc, d);
    if (lane >= d) inc += v;
  }
  const int T = __shfl(inc, 63);
  const int pref0 = inc - lsum;
  const int pref1 = pref0 + c0;

  float* __restrict__ mapO = out + (size_t)q * BQ_K;
  float* __restrict__ numO = out + (size_t)BQ_N1 * BQ_K + q;
  float* __restrict__ ptsO =
      out + (size_t)BQ_N1 * BQ_K + BQ_N1 + (size_t)q * BQ_K * 3;

  const bool fast = (T <= GIDXCAP);
  int H = 0;
  if (fast) {
    // Materialize candidate table: each lane writes its runs.
    for (int k = 0; k < c0; ++k) s_gidx[wid][pref0 + k] = st0 + k;
    for (int k = 0; k < c1; ++k) s_gidx[wid][pref1 + k] = st1 + k;

    // Flattened sweep: 1 LDS read + 1 L2 float4 gather per candidate.
    for (int s0 = 0; s0 < T; s0 += 64) {
      const int s = s0 + lane;
      bool within = false;
      float x2 = 0.f, y2 = 0.f, z2 = 0.f;
      int idx = 0;
      if (s < T) {
        const int g = s_gidx[wid][s];
        const float4 pt = sorted[g];
        x2 = pt.x; y2 = pt.y; z2 = pt.z;
        idx = __float_as_int(pt.w);
        // EXACT reference FP chain (round 5) — do not alter.
        const float n2 = (x2 * x2 + y2 * y2) + z2 * z2;
        float dot = x2 * x1;
        dot = __fmaf_rn(y1, y2, dot);
        dot = __fmaf_rn(z1, z2, dot);
        const float nsum = n1 + n2;
        const float twodot = 2.0f * dot;
        const float d2 = nsum - twodot;
        within = (d2 <= rsq);
      }
      const unsigned long long b = __ballot(within);
      if (b) {
        if (within) {
          const int pos = H + (int)__popcll(b & ((1ull << lane) - 1ull));
          if (pos < HITCAP)
            s_hits[wid][pos] = make_float4(x2, y2, z2, __int_as_float(idx));
        }
        H += (int)__popcll(b);
      }
    }
  }

  if (fast && H <= HITCAP) {
    const int nh = min(H, BQ_K);
    float4 h0 = make_float4(0.f, 0.f, 0.f, __int_as_float(0x7fffffff));
    float4 h1 = h0;
    if (lane < H) h0 = s_hits[wid][lane];
    if (lane + 64 < H) h1 = s_hits[wid][lane + 64];
    const int i0 = __float_as_int(h0.w);
    const int i1 = __float_as_int(h1.w);
    int r0 = 0, r1 = 0;
    for (int j = 0; j < H; ++j) {  // broadcast LDS reads
      const int bj = __float_as_int(s_hits[wid][j].w);
      r0 += (bj < i0) ? 1 : 0;
      r1 += (bj < i1) ? 1 : 0;
    }
    if (lane < H && r0 < BQ_K) {
      mapO[r0] = (float)i0;
      ptsO[r0 * 3 + 0] = h0.x;
      ptsO[r0 * 3 + 1] = h0.y;
      ptsO[r0 * 3 + 2] = h0.z;
    }
    if (lane + 64 < H && r1 < BQ_K) {
      mapO[r1] = (float)i1;
      ptsO[r1 * 3 + 0] = h1.x;
      ptsO[r1 * 3 + 1] = h1.y;
      ptsO[r1 * 3 + 2] = h1.z;
    }
    for (int sF = nh + lane; sF < BQ_K; sF += 64) {
      mapO[sF] = 0.0f;
      ptsO[sF * 3 + 0] = 0.0f;
      ptsO[sF * 3 + 1] = 0.0f;
      ptsO[sF * 3 + 2] = 0.0f;
    }
    if (lane == 0) numO[0] = (float)nh;
  } else {
    // Exact sequential fallback (capacity overflow safety net; P ~ 0).
    int filled = 0;
    for (int base = 0; base < BQ_N2; base += 64) {
      const int j = base + lane;
      const float x2 = p2[j * 3 + 0];
      const float y2 = p2[j * 3 + 1];
      const float z2 = p2[j * 3 + 2];
      const float n2 = (x2 * x2 + y2 * y2) + z2 * z2;
      float dot = x2 * x1;
      dot = __fmaf_rn(y1, y2, dot);
      dot = __fmaf_rn(z1, z2, dot);
      const float d2 = (n1 + n2) - 2.0f * dot;
      const bool within = (d2 <= rsq);
      const unsigned long long b = __ballot(within);
      if (b) {
        const int rank = (int)__popcll(b & ((1ull << lane) - 1ull));
        const int slot = filled + rank;
        if (within && slot < BQ_K) {
          mapO[slot] = (float)j;
          ptsO[slot * 3 + 0] = x2;
          ptsO[slot * 3 + 1] = y2;
          ptsO[slot * 3 + 2] = z2;
        }
        filled += (int)__popcll(b);
        if (filled >= BQ_K) { filled = BQ_K; break; }
      }
    }
    for (int sF = filled + lane; sF < BQ_K; sF += 64) {
      mapO[sF] = 0.0f;
      ptsO[sF * 3 + 0] = 0.0f;
      ptsO[sF * 3 + 1] = 0.0f;
      ptsO[sF * 3 + 2] = 0.0f;
    }
    if (lane == 0) numO[0] = (float)filled;
  }
}

// Round-5 brute-force kernel, kept as whole-problem fallback if ws too small.
__global__ __launch_bounds__(256) void bq_seq_kernel(
    const float* __restrict__ p1, const float* __restrict__ p2,
    float* __restrict__ out) {
#pragma clang fp contract(off)
  const int lane = threadIdx.x & 63;
  const int wave = threadIdx.x >> 6;
  const int q = blockIdx.x * 4 + wave;
  const float x1 = p1[q * 3 + 0], y1 = p1[q * 3 + 1], z1 = p1[q * 3 + 2];
  const float n1 = (x1 * x1 + y1 * y1) + z1 * z1;
  const float rsq = (float)(0.08 * 0.08);
  float* mapO = out + (size_t)q * BQ_K;
  float* numO = out + (size_t)BQ_N1 * BQ_K + q;
  float* ptsO = out + (size_t)BQ_N1 * BQ_K + BQ_N1 + (size_t)q * BQ_K * 3;
  int filled = 0;
  for (int base = 0; base < BQ_N2; base += 64) {
    const int j = base + lane;
    const float x2 = p2[j * 3 + 0], y2 = p2[j * 3 + 1], z2 = p2[j * 3 + 2];
    const float n2 = (x2 * x2 + y2 * y2) + z2 * z2;
    float dot = x2 * x1;
    dot = __fmaf_rn(y1, y2, dot);
    dot = __fmaf_rn(z1, z2, dot);
    const float d2 = (n1 + n2) - 2.0f * dot;
    const bool within = (d2 <= rsq);
    const unsigned long long b = __ballot(within);
    if (b) {
      const int rank = (int)__popcll(b & ((1ull << lane) - 1ull));
      const int slot = filled + rank;
      if (within && slot < BQ_K) {
        mapO[slot] = (float)j;
        ptsO[slot * 3 + 0] = x2;
        ptsO[slot * 3 + 1] = y2;
        ptsO[slot * 3 + 2] = z2;
      }
      filled += (int)__popcll(b);
      if (filled >= BQ_K) { filled = BQ_K; break; }
    }
  }
  for (int s = filled + lane; s < BQ_K; s += 64) {
    mapO[s] = 0.0f;
    ptsO[s * 3 + 0] = 0.0f;
    ptsO[s * 3 + 1] = 0.0f;
    ptsO[s * 3 + 2] = 0.0f;
  }
  if (lane == 0) numO[0] = (float)filled;
}

extern "C" void kernel_launch(void* const* d_in, const int* in_sizes, int n_in,
                              void* d_out, int out_size, void* d_ws,
                              size_t ws_size, hipStream_t stream) {
  const float* p1 = (const float*)d_in[0];
  const float* p2 = (const float*)d_in[1];
  float* out = (float*)d_out;

  if (ws_size < (size_t)WS_NEED) {
    bq_seq_kernel<<<BQ_N1 / 4, 256, 0, stream>>>(p1, p2, out);
    return;
  }

  char* ws = (char*)d_ws;
  int* cnt = (int*)(ws + WS_CNT_OFF);
  int* start = (int*)(ws + WS_START_OFF);
  float4* sorted = (float4*)(ws + WS_SORTED_OFF);

  bq_build_kernel<<<NPART, 1024, 0, stream>>>(p2, cnt, start, sorted);
  bq_query_kernel<<<BQ_N1 / 4, 256, 0, stream>>>(p1, p2, cnt, start, sorted,
                                                 out);
}